// Round 4
// baseline (354.404 us; speedup 1.0000x reference)
//
#include <hip/hip_runtime.h>
#include <hip/hip_bf16.h>
#include <stdint.h>

// Problem constants (shapes fixed by the reference)
#define DIM 1024
#define NH 16
#define HD 64
#define S_ORIG 8704
#define WIN 512          // L * WINDOW = 256*2

typedef __attribute__((ext_vector_type(8))) short short8;
typedef __attribute__((ext_vector_type(4))) float f32x4;

__device__ __forceinline__ float bf2f(unsigned short u) {
    return __uint_as_float(((unsigned int)u) << 16);
}
__device__ __forceinline__ unsigned short f2bf(float f) {
    unsigned int x = __float_as_uint(f);
    unsigned int r = x + 0x7fffu + ((x >> 16) & 1u);   // RNE
    return (unsigned short)(r >> 16);
}
// pack two fp32 -> bf16x2 (round-half-up; inputs are finite non-negative exp values)
__device__ __forceinline__ unsigned int pkbf(float a, float b) {
    unsigned int ua = (__float_as_uint(a) + 0x8000u) >> 16;
    unsigned int ub = (__float_as_uint(b) + 0x8000u) & 0xffff0000u;
    return ua | ub;
}

#define GLD_LDS(gptr, lptr) \
    __builtin_amdgcn_global_load_lds((const __attribute__((address_space(1))) void*)(gptr), \
                                     (__attribute__((address_space(3))) void*)(lptr), 16, 0, 0)

// ---------------- fp32 -> bf16 convert (x) ----------------
__global__ __launch_bounds__(256) void cvt_x(const float* __restrict__ x,
                                             unsigned short* __restrict__ xb) {
    int i = (blockIdx.x * 256 + threadIdx.x) * 4;   // total = 8704*1024, exact
    float4 v = *(const float4*)(x + i);
    ushort4 o;
    o.x = f2bf(v.x); o.y = f2bf(v.y); o.z = f2bf(v.z); o.w = f2bf(v.w);
    *(ushort4*)(xb + i) = o;
}

// ---------------- weight transpose + convert: Wt[n][k] = bf16(W[k][n]) ----------------
__global__ __launch_bounds__(256) void transpose_w(const float* __restrict__ w0,
                                                   const float* __restrict__ w1,
                                                   const float* __restrict__ w2,
                                                   const float* __restrict__ w3,
                                                   unsigned short* __restrict__ wt) {
    __shared__ float ts[64][65];
    const int z = blockIdx.z;
    const float* w = z == 0 ? w0 : z == 1 ? w1 : z == 2 ? w2 : w3;
    unsigned short* o = wt + (size_t)z * DIM * DIM;
    const int kb = blockIdx.x * 64, nb = blockIdx.y * 64;
    const int t = threadIdx.x, c = t & 63, r4 = t >> 6;
#pragma unroll
    for (int rr = 0; rr < 16; rr++) {
        int row = rr * 4 + r4;
        ts[row][c] = w[(size_t)(kb + row) * DIM + nb + c];
    }
    __syncthreads();
#pragma unroll
    for (int rr = 0; rr < 16; rr++) {
        int nl = rr * 4 + r4;
        o[(size_t)(nb + nl) * DIM + kb + c] = f2bf(ts[c][nl]);
    }
}

// ---------------- bf16 MFMA GEMM: C[M,N] = A[M,K] * Bt[N,K]^T + bias ----------------
// 128x128 tile, 4 waves, BK=32, global_load_lds width-16 staging (m97 pattern).
template <int OUTF32>
__global__ __launch_bounds__(256) void gemm_bf16(const unsigned short* __restrict__ A,
                                                 const unsigned short* __restrict__ Bt,
                                                 const float* __restrict__ b0,
                                                 const float* __restrict__ b1,
                                                 const float* __restrict__ b2,
                                                 void* __restrict__ Cout) {
    __shared__ __align__(16) unsigned short As[128 * 32];
    __shared__ __align__(16) unsigned short Bs[128 * 32];
    const int z = blockIdx.z;
    const unsigned short* B = Bt + (size_t)z * DIM * DIM;
    const float* bias = z == 0 ? b0 : (z == 1 ? b1 : b2);
    const int m0 = blockIdx.y * 128, n0 = blockIdx.x * 128;
    const int tid = threadIdx.x;
    const int lane = tid & 63, wv = tid >> 6;
    const int wr = wv >> 1, wc = wv & 1;
    const int quad = lane >> 4, r = lane & 15;

    f32x4 acc[4][4];
#pragma unroll
    for (int i = 0; i < 4; i++)
#pragma unroll
        for (int j = 0; j < 4; j++)
#pragma unroll
            for (int t4 = 0; t4 < 4; t4++) acc[i][j][t4] = 0.0f;

    const unsigned short* a_base = A + (size_t)m0 * DIM;
    const unsigned short* b_base = B + (size_t)n0 * DIM;
    const int c0 = wv * 128 + lane;
    const int r0 = c0 >> 2, o0 = (c0 & 3) * 8;
    const int c1 = c0 + 64;
    const int r1 = c1 >> 2, o1 = (c1 & 3) * 8;
    unsigned short* lA0 = &As[(size_t)(wv * 128) * 8];
    unsigned short* lA1 = &As[(size_t)(wv * 128 + 64) * 8];
    unsigned short* lB0 = &Bs[(size_t)(wv * 128) * 8];
    unsigned short* lB1 = &Bs[(size_t)(wv * 128 + 64) * 8];

    for (int k0 = 0; k0 < DIM; k0 += 32) {
        __syncthreads();
        GLD_LDS(a_base + (size_t)r0 * DIM + k0 + o0, lA0);
        GLD_LDS(a_base + (size_t)r1 * DIM + k0 + o1, lA1);
        GLD_LDS(b_base + (size_t)r0 * DIM + k0 + o0, lB0);
        GLD_LDS(b_base + (size_t)r1 * DIM + k0 + o1, lB1);
        __syncthreads();
        short8 af[4], bfr[4];
#pragma unroll
        for (int i = 0; i < 4; i++)
            af[i] = *(const short8*)&As[(wr * 64 + i * 16 + r) * 32 + quad * 8];
#pragma unroll
        for (int j = 0; j < 4; j++)
            bfr[j] = *(const short8*)&Bs[(wc * 64 + j * 16 + r) * 32 + quad * 8];
#pragma unroll
        for (int i = 0; i < 4; i++)
#pragma unroll
            for (int j = 0; j < 4; j++)
                acc[i][j] = __builtin_amdgcn_mfma_f32_16x16x32_bf16(af[i], bfr[j], acc[i][j], 0, 0, 0);
    }

#pragma unroll
    for (int i = 0; i < 4; i++) {
        const int row = m0 + wr * 64 + i * 16 + quad * 4;
#pragma unroll
        for (int j = 0; j < 4; j++) {
            const int col = n0 + wc * 64 + j * 16 + r;
            const float bvl = bias[col];
#pragma unroll
            for (int t4 = 0; t4 < 4; t4++) {
                float vv = acc[i][j][t4] + bvl;
                if (OUTF32) {
                    ((float*)Cout)[(size_t)(row + t4) * DIM + col] = vv;
                } else {
                    ((unsigned short*)Cout)[(size_t)z * S_ORIG * DIM + (size_t)(row + t4) * DIM + col] = f2bf(vv);
                }
            }
        }
    }
}

// ---------------- fused RMSNorm + RoPE (in-place on bf16 plane) ----------------
__global__ __launch_bounds__(256) void norm_rope(unsigned short* __restrict__ hq,
                                                 unsigned short* __restrict__ hk,
                                                 const float* __restrict__ gq,
                                                 const float* __restrict__ gk,
                                                 const float* __restrict__ fcos,
                                                 const float* __restrict__ fsin) {
    const int srow = blockIdx.x;
    const int z = blockIdx.y;
    unsigned short* h = z == 0 ? hq : hk;
    const float* g = z == 0 ? gq : gk;
    const int tid = threadIdx.x;
    const int base = tid * 4;
    unsigned short* hp = h + (size_t)srow * DIM;

    ushort4 raw = *(const ushort4*)(hp + base);
    float v0 = bf2f(raw.x), v1 = bf2f(raw.y), v2 = bf2f(raw.z), v3 = bf2f(raw.w);
    float ss = v0 * v0 + v1 * v1 + v2 * v2 + v3 * v3;
#pragma unroll
    for (int off = 1; off < 64; off <<= 1) ss += __shfl_xor(ss, off, 64);
    __shared__ float red[4];
    if ((tid & 63) == 0) red[tid >> 6] = ss;
    __syncthreads();
    ss = red[0] + red[1] + red[2] + red[3];
    const float rinv = rsqrtf(ss * (1.0f / DIM) + 1e-6f);

    float4 gv = *(const float4*)(g + base);
    v0 *= rinv * gv.x;
    v1 *= rinv * gv.y;
    v2 *= rinv * gv.z;
    v3 *= rinv * gv.w;

    const int i0 = (base & 63) >> 1;
    float2 cs = *(const float2*)(fcos + (size_t)srow * 32 + i0);
    float2 sn = *(const float2*)(fsin + (size_t)srow * 32 + i0);
    float ra0 = v0 * cs.x - v1 * sn.x;
    float rb0 = v0 * sn.x + v1 * cs.x;
    float ra1 = v2 * cs.y - v3 * sn.y;
    float rb1 = v2 * sn.y + v3 * cs.y;
    ushort4 o;
    o.x = f2bf(ra0); o.y = f2bf(rb0); o.z = f2bf(ra1); o.w = f2bf(rb1);
    *(ushort4*)(hp + base) = o;
}

// ---------------- dilated sliding-window attention, transposed-MFMA flash ----------------
// Round-4 structure: each block owns TWO q-tiles (128 queries) of one (head, stream) and
// slides a single K/V window over both: staging count 2*17 -> 18, barriers halved, and
// K/V MFMA fragments are hoisted to registers once per staged tile and reused by both
// q-tile passes (halves frag-read LDS traffic; LDS-BW floor ~51us -> ~33us).
// S^T layout (col = q = lane&15): per-lane softmax, no cross-lane reductions in the loop;
// Q pre-scale folds 1/sqrt(64) * log2(e) so exp() becomes a bare v_exp_f32 (exp2).
// Zero-pad keys (dilated pos >= 4352): K=V=0 -> exp2(0)=1, added to l analytically.
__global__ __launch_bounds__(256) void attn(const unsigned short* __restrict__ qkv,
                                            unsigned short* __restrict__ ob) {
    __shared__ __align__(16) unsigned short Ks[64 * 72];
    __shared__ __align__(16) unsigned short Vt[64 * 72];
    __shared__ __align__(16) unsigned short Ps[4][16 * 72];

    const int head = blockIdx.x >> 1;
    const int d = blockIdx.x & 1;
    const int qt0 = blockIdx.y * 2;
    const int tid = threadIdx.x;
    const int lane = tid & 63, wv = tid >> 6;
    const int quad = lane >> 4, r16 = lane & 15;

    const unsigned short* qb = qkv;
    const unsigned short* kb = qkv + (size_t)S_ORIG * DIM;
    const unsigned short* vb = qkv + (size_t)2 * S_ORIG * DIM;

    // --- per-lane queries for both owned tiles (B-operand of S^T) ---
    int qi[2], og_q[2];
    short8 qf[2][2];
#pragma unroll
    for (int t = 0; t < 2; t++) {
        qi[t] = (qt0 + t) * 64 + wv * 16 + r16;
        og_q[t] = ((qi[t] >> 8) << 9) + d * 256 + (qi[t] & 255);
        const unsigned short* qrow = qb + (size_t)og_q[t] * DIM + head * HD + quad * 8;
#pragma unroll
        for (int c = 0; c < 2; c++) {
            union { int4 i4; unsigned short u[8]; short8 s8; } in, outv;
            in.i4 = *(const int4*)(qrow + c * 32);
            // scale = 1/sqrt(64) * log2(e): scores land in log2 domain
#pragma unroll
            for (int j = 0; j < 8; j++) outv.u[j] = f2bf(bf2f(in.u[j]) * 0.18033688f);
            qf[t][c] = outv.s8;
        }
    }

    f32x4 oacc[2][4];   // O^T per tile: row d_local = quad*4+reg (nt), col q = r16
    float lsum[2] = {0.0f, 0.0f};
#pragma unroll
    for (int t = 0; t < 2; t++)
#pragma unroll
        for (int nt = 0; nt < 4; nt++)
#pragma unroll
            for (int rr = 0; rr < 4; rr++) oacc[t][nt][rr] = 0.0f;

    // real-key tiles only; kt>=68 are all-zero pad rows handled analytically below
    const int kt_lo = (qt0 - 8 > 0) ? (qt0 - 8) : 0;
    const int kt_hi = (qt0 + 9 < 67) ? (qt0 + 9) : 67;

    // per-thread staging coords (hoisted)
    const int st_row0 = tid >> 3, st_ch = (tid & 7) * 8;          // K: rows tid>>3, +32
    const int vt_kk = (tid & 31) * 2, vt_d0 = (tid >> 5) * 8;     // V^T

    for (int kt = kt_lo; kt <= kt_hi; kt++) {
        const int kbase = kt * 64;
        __syncthreads();   // previous tile's frag readers done before overwrite

        // stage K [kk][d], rows padded to 72 bf16 (kt<=67 => always in-bounds)
#pragma unroll
        for (int half = 0; half < 2; half++) {
            const int row = st_row0 + half * 32;
            const int kj = kbase + row;
            const int ok = ((kj >> 8) << 9) + d * 256 + (kj & 255);
            *(int4*)&Ks[row * 72 + st_ch] = *(const int4*)(kb + (size_t)ok * DIM + head * HD + st_ch);
        }
        // stage V transposed: Vt[d][kk]
        {
            const int kj0 = kbase + vt_kk;
            const int ok0 = ((kj0 >> 8) << 9) + d * 256 + (kj0 & 255);
            union { int4 i4; unsigned short u[8]; } a0, a1;
            a0.i4 = *(const int4*)(vb + (size_t)ok0 * DIM + head * HD + vt_d0);
            a1.i4 = *(const int4*)(vb + (size_t)(ok0 + 1) * DIM + head * HD + vt_d0);
#pragma unroll
            for (int i = 0; i < 8; i++) {
                unsigned int pack = (unsigned int)a0.u[i] | ((unsigned int)a1.u[i] << 16);
                *(unsigned int*)&Vt[(vt_d0 + i) * 72 + vt_kk] = pack;
            }
        }
        __syncthreads();

        // --- hoist K and V fragments once; reuse across both q-tile passes ---
        short8 kf[4][2], vf[4][2];
#pragma unroll
        for (int nt = 0; nt < 4; nt++) {
            kf[nt][0] = *(const short8*)&Ks[(nt * 16 + r16) * 72 + quad * 8];
            kf[nt][1] = *(const short8*)&Ks[(nt * 16 + r16) * 72 + 32 + quad * 8];
            vf[nt][0] = *(const short8*)&Vt[(nt * 16 + r16) * 72 + quad * 8];
            vf[nt][1] = *(const short8*)&Vt[(nt * 16 + r16) * 72 + 32 + quad * 8];
        }

        unsigned short* pw = &Ps[wv][0];
#pragma unroll
        for (int t = 0; t < 2; t++) {
            const int qtl = qt0 + t;
            if (kt < qtl - 8 || kt > qtl + 8) continue;   // block-uniform branch

            // --- S^T[kk][q]: A-op = K rows, B-op = this tile's Q frag ---
            f32x4 sv[4];
#pragma unroll
            for (int nt = 0; nt < 4; nt++) {
                f32x4 a = {0.0f, 0.0f, 0.0f, 0.0f};
                a = __builtin_amdgcn_mfma_f32_16x16x32_bf16(kf[nt][0], qf[t][0], a, 0, 0, 0);
                a = __builtin_amdgcn_mfma_f32_16x16x32_bf16(kf[nt][1], qf[t][1], a, 0, 0, 0);
                sv[nt] = a;
            }

            // --- exp2 (scores already in log2 domain), window mask on edge tiles only ---
            const bool edge = (kt == qtl - 8) || (kt == qtl + 8);
            // WAR guard: previous pass's P-frag reads must have completed before overwrite
            __asm__ volatile("s_waitcnt lgkmcnt(0)" ::: "memory");
#pragma unroll
            for (int nt = 0; nt < 4; nt++) {
                float p[4];
#pragma unroll
                for (int rr = 0; rr < 4; rr++) {
                    float e = exp2f(sv[nt][rr]);
                    if (edge) {
                        const int kj = kbase + nt * 16 + quad * 4 + rr;
                        const int dl = qi[t] - kj;
                        if (dl > WIN || dl < -WIN) e = 0.0f;
                    }
                    p[rr] = e;
                }
                lsum[t] += (p[0] + p[1]) + (p[2] + p[3]);
                uint2 pk;
                pk.x = pkbf(p[0], p[1]);
                pk.y = pkbf(p[2], p[3]);
                *(uint2*)&pw[r16 * 72 + nt * 16 + quad * 4] = pk;
            }
            __asm__ volatile("s_waitcnt lgkmcnt(0)" ::: "memory");

            // --- O^T += V^T * P^T : A-op = hoisted Vt frags, B-op = P frag ---
            short8 pf0 = *(const short8*)&pw[r16 * 72 + quad * 8];
            short8 pf1 = *(const short8*)&pw[r16 * 72 + 32 + quad * 8];
#pragma unroll
            for (int nt = 0; nt < 4; nt++) {
                oacc[t][nt] = __builtin_amdgcn_mfma_f32_16x16x32_bf16(vf[nt][0], pf0, oacc[t][nt], 0, 0, 0);
                oacc[t][nt] = __builtin_amdgcn_mfma_f32_16x16x32_bf16(vf[nt][1], pf1, oacc[t][nt], 0, 0, 0);
            }
        }
    }

    // --- finalize both tiles ---
#pragma unroll
    for (int t = 0; t < 2; t++) {
        float ls = lsum[t];
        ls += __shfl_xor(ls, 16, 64);
        ls += __shfl_xor(ls, 32, 64);
        // zero-pad keys (dilated pos >= 4352 -> orig >= 8704, K=V=0): exp2(0)=1 each
        const int cnt = (qi[t] + WIN < 4607 ? qi[t] + WIN : 4607) - 4351;
        if (cnt > 0) ls += (float)cnt;
        const float linv = 1.0f / ls;
#pragma unroll
        for (int nt = 0; nt < 4; nt++) {
            ushort4 o;
            o.x = f2bf(oacc[t][nt][0] * linv);
            o.y = f2bf(oacc[t][nt][1] * linv);
            o.z = f2bf(oacc[t][nt][2] * linv);
            o.w = f2bf(oacc[t][nt][3] * linv);
            *(ushort4*)&ob[(size_t)og_q[t] * DIM + head * HD + nt * 16 + quad * 4] = o;
        }
    }
}

// ---------------- launch ----------------
extern "C" void kernel_launch(void* const* d_in, const int* in_sizes, int n_in,
                              void* d_out, int out_size, void* d_ws, size_t ws_size,
                              hipStream_t stream) {
    const float* x    = (const float*)d_in[0];
    const float* fcos = (const float*)d_in[1];
    const float* fsin = (const float*)d_in[2];
    const float* wq   = (const float*)d_in[3];
    const float* bq   = (const float*)d_in[4];
    const float* wk   = (const float*)d_in[5];
    const float* bk   = (const float*)d_in[6];
    const float* wv   = (const float*)d_in[7];
    const float* bv   = (const float*)d_in[8];
    const float* wo   = (const float*)d_in[9];
    const float* bo   = (const float*)d_in[10];
    const float* gq   = (const float*)d_in[11];
    const float* gk   = (const float*)d_in[12];

    char* ws = (char*)d_ws;
    unsigned short* xb = (unsigned short*)(ws);
    unsigned short* wt = (unsigned short*)(ws + 17825792);
    unsigned short* h  = (unsigned short*)(ws + 26214400);
    unsigned short* ob = (unsigned short*)(ws + 79691776);
    float* outp = (float*)d_out;

    cvt_x<<<8704, 256, 0, stream>>>(x, xb);
    transpose_w<<<dim3(16, 16, 4), 256, 0, stream>>>(wq, wk, wv, wo, wt);
    gemm_bf16<0><<<dim3(8, 68, 3), 256, 0, stream>>>(xb, wt, bq, bk, bv, (void*)h);
    norm_rope<<<dim3(8704, 2), 256, 0, stream>>>(h, h + (size_t)S_ORIG * DIM, gq, gk, fcos, fsin);
    attn<<<dim3(32, 34), 256, 0, stream>>>(h, ob);
    gemm_bf16<1><<<dim3(8, 68, 1), 256, 0, stream>>>(ob, wt + (size_t)3 * DIM * DIM, bo, bo, bo, (void*)outp);
}

// Round 5
// 331.877 us; speedup vs baseline: 1.0679x; 1.0679x over previous
//
#include <hip/hip_runtime.h>
#include <hip/hip_bf16.h>
#include <stdint.h>

// Problem constants (shapes fixed by the reference)
#define DIM 1024
#define NH 16
#define HD 64
#define S_ORIG 8704
#define WIN 512          // L * WINDOW = 256*2

typedef __attribute__((ext_vector_type(8))) short short8;
typedef __attribute__((ext_vector_type(4))) float f32x4;

__device__ __forceinline__ float bf2f(unsigned short u) {
    return __uint_as_float(((unsigned int)u) << 16);
}
__device__ __forceinline__ unsigned short f2bf(float f) {
    unsigned int x = __float_as_uint(f);
    unsigned int r = x + 0x7fffu + ((x >> 16) & 1u);   // RNE
    return (unsigned short)(r >> 16);
}
// pack two fp32 -> bf16x2 (round-half-up; inputs are finite non-negative exp values)
__device__ __forceinline__ unsigned int pkbf(float a, float b) {
    unsigned int ua = (__float_as_uint(a) + 0x8000u) >> 16;
    unsigned int ub = (__float_as_uint(b) + 0x8000u) & 0xffff0000u;
    return ua | ub;
}

#define GLD_LDS(gptr, lptr) \
    __builtin_amdgcn_global_load_lds((const __attribute__((address_space(1))) void*)(gptr), \
                                     (__attribute__((address_space(3))) void*)(lptr), 16, 0, 0)

// ---------------- fp32 -> bf16 convert (x) ----------------
__global__ __launch_bounds__(256) void cvt_x(const float* __restrict__ x,
                                             unsigned short* __restrict__ xb) {
    int i = (blockIdx.x * 256 + threadIdx.x) * 4;   // total = 8704*1024, exact
    float4 v = *(const float4*)(x + i);
    ushort4 o;
    o.x = f2bf(v.x); o.y = f2bf(v.y); o.z = f2bf(v.z); o.w = f2bf(v.w);
    *(ushort4*)(xb + i) = o;
}

// ---------------- weight transpose + convert: Wt[n][k] = bf16(W[k][n]) ----------------
__global__ __launch_bounds__(256) void transpose_w(const float* __restrict__ w0,
                                                   const float* __restrict__ w1,
                                                   const float* __restrict__ w2,
                                                   const float* __restrict__ w3,
                                                   unsigned short* __restrict__ wt) {
    __shared__ float ts[64][65];
    const int z = blockIdx.z;
    const float* w = z == 0 ? w0 : z == 1 ? w1 : z == 2 ? w2 : w3;
    unsigned short* o = wt + (size_t)z * DIM * DIM;
    const int kb = blockIdx.x * 64, nb = blockIdx.y * 64;
    const int t = threadIdx.x, c = t & 63, r4 = t >> 6;
#pragma unroll
    for (int rr = 0; rr < 16; rr++) {
        int row = rr * 4 + r4;
        ts[row][c] = w[(size_t)(kb + row) * DIM + nb + c];
    }
    __syncthreads();
#pragma unroll
    for (int rr = 0; rr < 16; rr++) {
        int nl = rr * 4 + r4;
        o[(size_t)(nb + nl) * DIM + kb + c] = f2bf(ts[c][nl]);
    }
}

// ---------------- bf16 MFMA GEMM: C[M,N] = A[M,K] * Bt[N,K]^T + bias ----------------
// 128x128 tile, 4 waves, BK=32, global_load_lds width-16 staging (m97 pattern)
// + XOR bank swizzle: LDS chunk c holds global col ((c&3)^((c>>3)&3))*8, which turns
// the frag-read 8-way bank conflict (64B row stride) into conflict-free 2-way.
template <int OUTF32>
__global__ __launch_bounds__(256) void gemm_bf16(const unsigned short* __restrict__ A,
                                                 const unsigned short* __restrict__ Bt,
                                                 const float* __restrict__ b0,
                                                 const float* __restrict__ b1,
                                                 const float* __restrict__ b2,
                                                 void* __restrict__ Cout) {
    __shared__ __align__(16) unsigned short As[128 * 32];
    __shared__ __align__(16) unsigned short Bs[128 * 32];
    const int z = blockIdx.z;
    const unsigned short* B = Bt + (size_t)z * DIM * DIM;
    const float* bias = z == 0 ? b0 : (z == 1 ? b1 : b2);
    const int m0 = blockIdx.y * 128, n0 = blockIdx.x * 128;
    const int tid = threadIdx.x;
    const int lane = tid & 63, wv = tid >> 6;
    const int wr = wv >> 1, wc = wv & 1;
    const int quad = lane >> 4, r = lane & 15;

    f32x4 acc[4][4];
#pragma unroll
    for (int i = 0; i < 4; i++)
#pragma unroll
        for (int j = 0; j < 4; j++)
#pragma unroll
            for (int t4 = 0; t4 < 4; t4++) acc[i][j][t4] = 0.0f;

    const unsigned short* a_base = A + (size_t)m0 * DIM;
    const unsigned short* b_base = B + (size_t)n0 * DIM;
    // staging chunk c: row = c>>2, swizzled col = ((c&3) ^ ((c>>3)&3))*8
    const int c0 = wv * 128 + lane;
    const int r0 = c0 >> 2, o0 = (((c0 & 3) ^ ((c0 >> 3) & 3))) * 8;
    const int c1 = c0 + 64;
    const int r1 = c1 >> 2, o1 = (((c1 & 3) ^ ((c1 >> 3) & 3))) * 8;
    unsigned short* lA0 = &As[(size_t)(wv * 128) * 8];
    unsigned short* lA1 = &As[(size_t)(wv * 128 + 64) * 8];
    unsigned short* lB0 = &Bs[(size_t)(wv * 128) * 8];
    unsigned short* lB1 = &Bs[(size_t)(wv * 128 + 64) * 8];

    // frag-read physical chunk-in-row: j' = quad ^ ((R>>1)&3); R = base + r with base mult of 8
    const int jsw = (quad ^ ((r >> 1) & 3)) * 8;

    for (int k0 = 0; k0 < DIM; k0 += 32) {
        __syncthreads();
        GLD_LDS(a_base + (size_t)r0 * DIM + k0 + o0, lA0);
        GLD_LDS(a_base + (size_t)r1 * DIM + k0 + o1, lA1);
        GLD_LDS(b_base + (size_t)r0 * DIM + k0 + o0, lB0);
        GLD_LDS(b_base + (size_t)r1 * DIM + k0 + o1, lB1);
        __syncthreads();
        short8 af[4], bfr[4];
#pragma unroll
        for (int i = 0; i < 4; i++)
            af[i] = *(const short8*)&As[(wr * 64 + i * 16 + r) * 32 + jsw];
#pragma unroll
        for (int j = 0; j < 4; j++)
            bfr[j] = *(const short8*)&Bs[(wc * 64 + j * 16 + r) * 32 + jsw];
#pragma unroll
        for (int i = 0; i < 4; i++)
#pragma unroll
            for (int j = 0; j < 4; j++)
                acc[i][j] = __builtin_amdgcn_mfma_f32_16x16x32_bf16(af[i], bfr[j], acc[i][j], 0, 0, 0);
    }

#pragma unroll
    for (int i = 0; i < 4; i++) {
        const int row = m0 + wr * 64 + i * 16 + quad * 4;
#pragma unroll
        for (int j = 0; j < 4; j++) {
            const int col = n0 + wc * 64 + j * 16 + r;
            const float bvl = bias[col];
#pragma unroll
            for (int t4 = 0; t4 < 4; t4++) {
                float vv = acc[i][j][t4] + bvl;
                if (OUTF32) {
                    ((float*)Cout)[(size_t)(row + t4) * DIM + col] = vv;
                } else {
                    ((unsigned short*)Cout)[(size_t)z * S_ORIG * DIM + (size_t)(row + t4) * DIM + col] = f2bf(vv);
                }
            }
        }
    }
}

// ---------------- fused RMSNorm + RoPE (in-place on bf16 plane) ----------------
__global__ __launch_bounds__(256) void norm_rope(unsigned short* __restrict__ hq,
                                                 unsigned short* __restrict__ hk,
                                                 const float* __restrict__ gq,
                                                 const float* __restrict__ gk,
                                                 const float* __restrict__ fcos,
                                                 const float* __restrict__ fsin) {
    const int srow = blockIdx.x;
    const int z = blockIdx.y;
    unsigned short* h = z == 0 ? hq : hk;
    const float* g = z == 0 ? gq : gk;
    const int tid = threadIdx.x;
    const int base = tid * 4;
    unsigned short* hp = h + (size_t)srow * DIM;

    ushort4 raw = *(const ushort4*)(hp + base);
    float v0 = bf2f(raw.x), v1 = bf2f(raw.y), v2 = bf2f(raw.z), v3 = bf2f(raw.w);
    float ss = v0 * v0 + v1 * v1 + v2 * v2 + v3 * v3;
#pragma unroll
    for (int off = 1; off < 64; off <<= 1) ss += __shfl_xor(ss, off, 64);
    __shared__ float red[4];
    if ((tid & 63) == 0) red[tid >> 6] = ss;
    __syncthreads();
    ss = red[0] + red[1] + red[2] + red[3];
    const float rinv = rsqrtf(ss * (1.0f / DIM) + 1e-6f);

    float4 gv = *(const float4*)(g + base);
    v0 *= rinv * gv.x;
    v1 *= rinv * gv.y;
    v2 *= rinv * gv.z;
    v3 *= rinv * gv.w;

    const int i0 = (base & 63) >> 1;
    float2 cs = *(const float2*)(fcos + (size_t)srow * 32 + i0);
    float2 sn = *(const float2*)(fsin + (size_t)srow * 32 + i0);
    float ra0 = v0 * cs.x - v1 * sn.x;
    float rb0 = v0 * sn.x + v1 * cs.x;
    float ra1 = v2 * cs.y - v3 * sn.y;
    float rb1 = v2 * sn.y + v3 * cs.y;
    ushort4 o;
    o.x = f2bf(ra0); o.y = f2bf(rb0); o.z = f2bf(ra1); o.w = f2bf(rb1);
    *(ushort4*)(hp + base) = o;
}

// ---------------- dilated sliding-window attention, transposed-MFMA flash ----------------
// Round-3 structure (proven 92.8us; round-4's 2-qtile variant regressed on occupancy:
// VGPR 44->104, occ 42->20%). grid: (32 = head*2+stream, 68 qtiles). XCD swizzle via
// grid order. S^T = K*Q^T (col = q = lane&15): per-lane softmax, no in-loop cross-lane
// reductions; fixed-max softmax (scores bounded); l reduced once at the end.
// Zero-pad key tiles (kt>=68) contribute l += count analytically (V rows are zero).
__global__ __launch_bounds__(256) void attn(const unsigned short* __restrict__ qkv,
                                            unsigned short* __restrict__ ob) {
    __shared__ __align__(16) unsigned short Ks[64 * 72];
    __shared__ __align__(16) unsigned short Vt[64 * 72];
    __shared__ __align__(16) unsigned short Ps[4][16 * 72];

    const int head = blockIdx.x >> 1;
    const int d = blockIdx.x & 1;
    const int qt = blockIdx.y;
    const int tid = threadIdx.x;
    const int lane = tid & 63, wv = tid >> 6;
    const int quad = lane >> 4, r16 = lane & 15;

    const unsigned short* qb = qkv;
    const unsigned short* kb = qkv + (size_t)S_ORIG * DIM;
    const unsigned short* vb = qkv + (size_t)2 * S_ORIG * DIM;

    // --- this lane's query (B-operand of S^T): q = r16 within wave tile ---
    const int qi = qt * 64 + wv * 16 + r16;
    const int og_q = ((qi >> 8) << 9) + d * 256 + (qi & 255);
    short8 qf[2];
    {
        const unsigned short* qrow = qb + (size_t)og_q * DIM + head * HD + quad * 8;
#pragma unroll
        for (int c = 0; c < 2; c++) {
            union { int4 i4; unsigned short u[8]; short8 s8; } in, outv;
            in.i4 = *(const int4*)(qrow + c * 32);
#pragma unroll
            for (int j = 0; j < 8; j++) outv.u[j] = f2bf(bf2f(in.u[j]) * 0.125f);
            qf[c] = outv.s8;
        }
    }

    f32x4 oacc[4];     // O^T: row d_local = quad*4+reg (tile nt), col q = r16
    float lsum = 0.0f;
#pragma unroll
    for (int nt = 0; nt < 4; nt++)
#pragma unroll
        for (int rr = 0; rr < 4; rr++) oacc[nt][rr] = 0.0f;

    // real-key tiles only; kt>=68 are all-zero pad rows handled analytically below
    const int kt_lo = (qt - 8 > 0) ? (qt - 8) : 0;
    const int kt_hi = (qt + 8 < 67) ? (qt + 8) : 67;

    // per-thread staging coords (hoisted)
    const int st_row0 = tid >> 3, st_ch = (tid & 7) * 8;          // K: rows tid>>3, +32
    const int vt_kk = (tid & 31) * 2, vt_d0 = (tid >> 5) * 8;     // V^T

    for (int kt = kt_lo; kt <= kt_hi; kt++) {
        const int kbase = kt * 64;
        __syncthreads();   // previous tile's frag readers done before overwrite

        // stage K [kk][d], rows padded to 72 bf16 (kt<=67 => always in-bounds)
#pragma unroll
        for (int half = 0; half < 2; half++) {
            const int row = st_row0 + half * 32;
            const int kj = kbase + row;
            const int ok = ((kj >> 8) << 9) + d * 256 + (kj & 255);
            *(int4*)&Ks[row * 72 + st_ch] = *(const int4*)(kb + (size_t)ok * DIM + head * HD + st_ch);
        }
        // stage V transposed: Vt[d][kk]
        {
            const int kj0 = kbase + vt_kk;
            const int ok0 = ((kj0 >> 8) << 9) + d * 256 + (kj0 & 255);
            union { int4 i4; unsigned short u[8]; } a0, a1;
            a0.i4 = *(const int4*)(vb + (size_t)ok0 * DIM + head * HD + vt_d0);
            a1.i4 = *(const int4*)(vb + (size_t)(ok0 + 1) * DIM + head * HD + vt_d0);
#pragma unroll
            for (int i = 0; i < 8; i++) {
                unsigned int pack = (unsigned int)a0.u[i] | ((unsigned int)a1.u[i] << 16);
                *(unsigned int*)&Vt[(vt_d0 + i) * 72 + vt_kk] = pack;
            }
        }
        __syncthreads();

        // --- S^T[kk][q]: A-op = K rows, B-op = Q frag ---
        f32x4 sv[4];
#pragma unroll
        for (int nt = 0; nt < 4; nt++) {
            short8 k0f = *(const short8*)&Ks[(nt * 16 + r16) * 72 + quad * 8];
            short8 k1f = *(const short8*)&Ks[(nt * 16 + r16) * 72 + 32 + quad * 8];
            f32x4 a = {0.0f, 0.0f, 0.0f, 0.0f};
            a = __builtin_amdgcn_mfma_f32_16x16x32_bf16(k0f, qf[0], a, 0, 0, 0);
            a = __builtin_amdgcn_mfma_f32_16x16x32_bf16(k1f, qf[1], a, 0, 0, 0);
            sv[nt] = a;
        }

        // --- exp (no max subtraction: scores bounded), window mask on edge tiles only ---
        const bool edge = (kt == qt - 8) || (kt == qt + 8);
        unsigned short* pw = &Ps[wv][0];
#pragma unroll
        for (int nt = 0; nt < 4; nt++) {
            float p[4];
#pragma unroll
            for (int rr = 0; rr < 4; rr++) {
                float e = __expf(sv[nt][rr]);
                if (edge) {
                    const int kj = kbase + nt * 16 + quad * 4 + rr;
                    const int dl = qi - kj;
                    if (dl > WIN || dl < -WIN) e = 0.0f;
                }
                p[rr] = e;
            }
            lsum += (p[0] + p[1]) + (p[2] + p[3]);
            uint2 pk;
            pk.x = pkbf(p[0], p[1]);
            pk.y = pkbf(p[2], p[3]);
            *(uint2*)&pw[r16 * 72 + nt * 16 + quad * 4] = pk;
        }
        __asm__ volatile("s_waitcnt lgkmcnt(0)" ::: "memory");

        // --- O^T += V^T * P^T : A-op = Vt rows, B-op = P frag (A-layout of P) ---
        short8 pf0 = *(const short8*)&pw[r16 * 72 + quad * 8];
        short8 pf1 = *(const short8*)&pw[r16 * 72 + 32 + quad * 8];
#pragma unroll
        for (int nt = 0; nt < 4; nt++) {
            short8 v0f = *(const short8*)&Vt[(nt * 16 + r16) * 72 + quad * 8];
            short8 v1f = *(const short8*)&Vt[(nt * 16 + r16) * 72 + 32 + quad * 8];
            oacc[nt] = __builtin_amdgcn_mfma_f32_16x16x32_bf16(v0f, pf0, oacc[nt], 0, 0, 0);
            oacc[nt] = __builtin_amdgcn_mfma_f32_16x16x32_bf16(v1f, pf1, oacc[nt], 0, 0, 0);
        }
    }

    // --- final l: reduce across the 4 quads (other lanes hold other kk of same q) ---
    lsum += __shfl_xor(lsum, 16, 64);
    lsum += __shfl_xor(lsum, 32, 64);
    // zero-pad keys (dilated pos >= 4352 -> orig >= 8704, K=V=0): score 0 -> exp=1 each
    {
        const int cnt = (qi + WIN < 4607 ? qi + WIN : 4607) - 4351;
        if (cnt > 0) lsum += (float)cnt;
    }
    const float linv = 1.0f / lsum;

    // --- write O: lane owns q = r16; 4 consecutive dims per nt ---
#pragma unroll
    for (int nt = 0; nt < 4; nt++) {
        ushort4 o;
        o.x = f2bf(oacc[nt][0] * linv);
        o.y = f2bf(oacc[nt][1] * linv);
        o.z = f2bf(oacc[nt][2] * linv);
        o.w = f2bf(oacc[nt][3] * linv);
        *(ushort4*)&ob[(size_t)og_q * DIM + head * HD + nt * 16 + quad * 4] = o;
    }
}

// ---------------- launch ----------------
extern "C" void kernel_launch(void* const* d_in, const int* in_sizes, int n_in,
                              void* d_out, int out_size, void* d_ws, size_t ws_size,
                              hipStream_t stream) {
    const float* x    = (const float*)d_in[0];
    const float* fcos = (const float*)d_in[1];
    const float* fsin = (const float*)d_in[2];
    const float* wq   = (const float*)d_in[3];
    const float* bq   = (const float*)d_in[4];
    const float* wk   = (const float*)d_in[5];
    const float* bk   = (const float*)d_in[6];
    const float* wv   = (const float*)d_in[7];
    const float* bv   = (const float*)d_in[8];
    const float* wo   = (const float*)d_in[9];
    const float* bo   = (const float*)d_in[10];
    const float* gq   = (const float*)d_in[11];
    const float* gk   = (const float*)d_in[12];

    char* ws = (char*)d_ws;
    unsigned short* xb = (unsigned short*)(ws);
    unsigned short* wt = (unsigned short*)(ws + 17825792);
    unsigned short* h  = (unsigned short*)(ws + 26214400);
    unsigned short* ob = (unsigned short*)(ws + 79691776);
    float* outp = (float*)d_out;

    cvt_x<<<8704, 256, 0, stream>>>(x, xb);
    transpose_w<<<dim3(16, 16, 4), 256, 0, stream>>>(wq, wk, wv, wo, wt);
    gemm_bf16<0><<<dim3(8, 68, 3), 256, 0, stream>>>(xb, wt, bq, bk, bv, (void*)h);
    norm_rope<<<dim3(8704, 2), 256, 0, stream>>>(h, h + (size_t)S_ORIG * DIM, gq, gk, fcos, fsin);
    attn<<<dim3(32, 68), 256, 0, stream>>>(h, ob);
    gemm_bf16<1><<<dim3(8, 68, 1), 256, 0, stream>>>(ob, wt + (size_t)3 * DIM * DIM, bo, bo, bo, (void*)outp);
}